// Round 10
// baseline (26157.770 us; speedup 1.0000x reference)
//
#include <hip/hip_runtime.h>
#include <math.h>

// Problem constants
#define D_MODEL 1024
#define N_WIN   240
#define TOK     256
#define NH      16
#define DH      64
#define CHUNK   8
#define NCHUNK  30
#define WIN     ((size_t)TOK * D_MODEL)

typedef unsigned short ushort_t;
typedef unsigned long long ull_t;
typedef __attribute__((ext_vector_type(8))) short short8;
typedef __attribute__((ext_vector_type(4))) float floatx4;

__device__ __forceinline__ ushort_t f2bf(float f) {   // RNE
    unsigned u = __float_as_uint(f);
    unsigned lsb = (u >> 16) & 1u;
    u += 0x7fffu + lsb;
    return (ushort_t)(u >> 16);
}

// ---------------------------------------------------------------------------
// Coherence primitives (round-9 proven):
//  - st2_wt: 2B write-through store (lands at coherence point / IC).
//  - ld8_sys/ld16_sys: system-scope relaxed loads (bypass L1/L2, IC-fresh,
//    vmcnt-pipelined). Used ONLY for the AO scan buffers.
//  - No cache invalidation anywhere -> weights/Q stay L2-hot across steps.
// ---------------------------------------------------------------------------
__device__ __forceinline__ void st2_wt(ushort_t* p, ushort_t v) {
    unsigned vv = v;
    asm volatile("global_store_short %0, %1, off sc1"
                 :: "v"(p), "v"(vv) : "memory");
}
__device__ __forceinline__ void rel_drain() {
    asm volatile("s_waitcnt vmcnt(0)" ::: "memory");
}
__device__ __forceinline__ ull_t ld8_sys(const ushort_t* p) {
    return __hip_atomic_load((const ull_t*)p, __ATOMIC_RELAXED,
                             __HIP_MEMORY_SCOPE_SYSTEM);
}
__device__ __forceinline__ short8 ld16_sys(const ushort_t* p) {
    union { ull_t u[2]; short8 s; } c;
    c.u[0] = ld8_sys(p); c.u[1] = ld8_sys(p + 4);
    return c.s;
}

// async global->LDS, 16B per lane (phase-1 GEMM staging)
#define GLDS(g, l) __builtin_amdgcn_global_load_lds( \
    (const __attribute__((address_space(1))) unsigned int*)(g), \
    (__attribute__((address_space(3))) unsigned int*)(l), 16, 0, 0)

// ---------------------------------------------------------------------------
// Grid barrier (tree, fence-free): all threads drain stores, WG syncs, tid0
// signals agent-scope counters and spins on release. 4 subs x 8 arrivals.
// ---------------------------------------------------------------------------
__device__ __forceinline__ void grid_bar(unsigned* base, int g, unsigned s)
{
    rel_drain();
    __syncthreads();
    if (threadIdx.x == 0) {
        unsigned old = __hip_atomic_fetch_add(base + g * 32, 1u,
                __ATOMIC_RELAXED, __HIP_MEMORY_SCOPE_AGENT);
        if (old == 8u * s - 1u) {
            unsigned r = __hip_atomic_fetch_add(base + 256, 1u,
                    __ATOMIC_RELAXED, __HIP_MEMORY_SCOPE_AGENT);
            if (r == 4u * s - 1u)
                __hip_atomic_store(base + 288, s, __ATOMIC_RELAXED,
                                   __HIP_MEMORY_SCOPE_AGENT);
        }
        while (__hip_atomic_load(base + 288, __ATOMIC_RELAXED,
                                 __HIP_MEMORY_SCOPE_AGENT) < s)
            __builtin_amdgcn_s_sleep(1);
    }
    __syncthreads();
}

// ---------------------------------------------------------------------------
// fp32 -> bf16 cast
// ---------------------------------------------------------------------------
__global__ __launch_bounds__(256) void cast_bf_k(
    const float* __restrict__ s, ushort_t* __restrict__ d, int n)
{
    int i = (blockIdx.x * 256 + threadIdx.x) * 4;
    if (i >= n) return;
    float4 v = *(const float4*)(s + i);
    ushort4 o;
    o.x = f2bf(v.x); o.y = f2bf(v.y); o.z = f2bf(v.z); o.w = f2bf(v.w);
    *(ushort4*)(d + i) = o;
}

// 64x64-tile bf16 transpose: dst[c][r] = src[r][c], both 1024x1024
__global__ __launch_bounds__(256) void transpose_k(
    const ushort_t* __restrict__ src, ushort_t* __restrict__ dst)
{
    __shared__ ushort_t t[64][65];
    const int bx = blockIdx.x * 64, by = blockIdx.y * 64;
    const int c = threadIdx.x & 63, r0 = threadIdx.x >> 6;
#pragma unroll
    for (int k = 0; k < 16; ++k) {
        int r = r0 + k * 4;
        t[r][c] = src[(size_t)(by + r) * 1024 + bx + c];
    }
    __syncthreads();
#pragma unroll
    for (int k = 0; k < 16; ++k) {
        int r = r0 + k * 4;
        dst[(size_t)(bx + r) * 1024 + by + c] = t[c][r];
    }
}

// bc[n] = b_in2[1024+n] + dot(w_in2 row (1024+n), b_out2), fp32, n in [0,2048)
__global__ __launch_bounds__(256) void bc_k(
    const float* __restrict__ w_in2, const float* __restrict__ b_in2,
    const float* __restrict__ b_out2, float* __restrict__ bc)
{
    int n = blockIdx.x * 256 + threadIdx.x;
    const float* row = w_in2 + (size_t)(1024 + n) * 1024;
    float s = b_in2[1024 + n];
    for (int j = 0; j < 1024; j += 4) {
        float4 w = *(const float4*)(row + j);
        float4 b = *(const float4*)(b_out2 + j);
        s += w.x * b.x + w.y * b.y + w.z * b.z + w.w * b.w;
    }
    bc[n] = s;
}

// ---------------------------------------------------------------------------
// Phase-1 bf16 MFMA GEMM core (m97 structure), 128x128 tile, BK=32.
// ---------------------------------------------------------------------------
template<bool GATHER>
__device__ __forceinline__ void gemm_core(
    const ushort_t* __restrict__ A, int lda, int w0,
    const ushort_t* __restrict__ W, const float* __restrict__ bias,
    ushort_t* __restrict__ Cb, float* __restrict__ Cf, int ldc,
    int K, int m0, int n0, int co, int relu)
{
    __shared__ ushort_t As[128 * 32];
    __shared__ ushort_t Bs[128 * 32];
    const int tid = threadIdx.x;
    const int wave = tid >> 6, lane = tid & 63;
    const int wm = wave & 1, wn = wave >> 1;

    int r0 = m0 + (tid >> 2), r1 = r0 + 64;
    if (GATHER) {
        r0 = (w0 + (r0 >> 8)) * 16 + (r0 & 255);
        r1 = (w0 + (r1 >> 8)) * 16 + (r1 & 255);
    }
    const int kcol = (tid & 3) * 8;
    const ushort_t* gA0 = A + (size_t)r0 * lda + kcol;
    const ushort_t* gA1 = A + (size_t)r1 * lda + kcol;
    const ushort_t* pW  = W + (size_t)n0 * K;
    const ushort_t* gB0 = pW + (size_t)(tid >> 2) * K + kcol;
    const ushort_t* gB1 = gB0 + (size_t)64 * K;
    ushort_t* lA = As + wave * 512;
    ushort_t* lB = Bs + wave * 512;

    floatx4 acc[4][4];
#pragma unroll
    for (int i = 0; i < 4; ++i)
#pragma unroll
        for (int j = 0; j < 4; ++j) acc[i][j] = (floatx4){0.f, 0.f, 0.f, 0.f};

    const int fr = lane & 15, fk = (lane >> 4) * 8;
    const int arow = (wm * 64 + fr) * 32 + fk;
    const int brow = (wn * 64 + fr) * 32 + fk;

    for (int k0 = 0; k0 < K; k0 += 32) {
        GLDS(gA0 + k0, lA);
        GLDS(gA1 + k0, lA + 2048);
        GLDS(gB0 + k0, lB);
        GLDS(gB1 + k0, lB + 2048);
        __syncthreads();
        short8 a[4], b[4];
#pragma unroll
        for (int mi = 0; mi < 4; ++mi) a[mi] = *(const short8*)&As[arow + mi * 512];
#pragma unroll
        for (int ni = 0; ni < 4; ++ni) b[ni] = *(const short8*)&Bs[brow + ni * 512];
#pragma unroll
        for (int mi = 0; mi < 4; ++mi)
#pragma unroll
            for (int ni = 0; ni < 4; ++ni)
                acc[mi][ni] = __builtin_amdgcn_mfma_f32_16x16x32_bf16(
                    a[mi], b[ni], acc[mi][ni], 0, 0, 0);
        __syncthreads();
    }

    const int crq = (lane >> 4) * 4;
    const int ccol = lane & 15;
#pragma unroll
    for (int mi = 0; mi < 4; ++mi) {
#pragma unroll
        for (int ni = 0; ni < 4; ++ni) {
            int lc = wn * 64 + ni * 16 + ccol;
            float bz = bias[n0 + lc];
#pragma unroll
            for (int rg = 0; rg < 4; ++rg) {
                int row = m0 + wm * 64 + mi * 16 + crq + rg;
                float v = acc[mi][ni][rg] + bz;
                if (relu) v = fmaxf(v, 0.f);
                size_t off = (size_t)row * ldc + co + lc;
                if (Cb) Cb[off] = f2bf(v);
                if (Cf) Cf[off] = v;
            }
        }
    }
}

__global__ __launch_bounds__(256) void gemm_bf_k(
    const ushort_t* __restrict__ A, int lda,
    const ushort_t* __restrict__ W, const float* __restrict__ bias,
    ushort_t* __restrict__ Cb, float* __restrict__ Cf, int ldc,
    int K, int relu)
{
    gemm_core<false>(A, lda, 0, W, bias, Cb, Cf, ldc, K,
                     blockIdx.y * 128, blockIdx.x * 128, blockIdx.x * 128, relu);
}

__global__ __launch_bounds__(256) void gemm_qkv_k(
    const ushort_t* __restrict__ path_bf, const ushort_t* __restrict__ W,
    const float* __restrict__ bias, ushort_t* __restrict__ Cb, int w0)
{
    gemm_core<true>(path_bf, 1024, w0, W, bias, Cb, nullptr, 3072, 1024,
                    blockIdx.y * 128, blockIdx.x * 128, blockIdx.x * 128, 0);
}

// ---------------------------------------------------------------------------
// Phase-1 MFMA attention (unchanged).
// ---------------------------------------------------------------------------
#define PLD 260
#define VLD 132

struct AttnShared {
    ushort_t P[64 * PLD];
    ushort_t VT[64 * VLD];
    float    l[64];
};

__global__ __launch_bounds__(256) void attn_mfma_k(
    const ushort_t* __restrict__ qkv, ushort_t* __restrict__ ao)
{
    __shared__ AttnShared sh;
    const int rs = blockIdx.x, h = blockIdx.y, b = blockIdx.z;
    const ushort_t* base = qkv + (size_t)b * TOK * 3072;
    const ushort_t* Q = base;
    const ushort_t* K = base + 1024;
    const ushort_t* V = base + 2048;
    ushort_t* O = ao + (size_t)b * TOK * 1024;
    const int ldq = 3072, ldkv = 3072, ldo = 1024;
    const int tid = threadIdx.x;
    const int wave = tid >> 6, lane = tid & 63;
    const int fr = lane & 15, q = lane >> 4, fk = q * 8;
    const ushort_t* Qh = Q + (size_t)(rs * 64) * ldq + h * 64;
    const ushort_t* Kh = K + h * 64;
    const ushort_t* Vh = V + h * 64;
    const int m0 = wave * 16;

    floatx4 s[16];
#pragma unroll
    for (int nt = 0; nt < 16; ++nt) s[nt] = (floatx4){0.f, 0.f, 0.f, 0.f};
#pragma unroll
    for (int kc = 0; kc < 64; kc += 32) {
        short8 a = *(const short8*)(Qh + (size_t)(m0 + fr) * ldq + kc + fk);
#pragma unroll
        for (int nt = 0; nt < 16; ++nt) {
            short8 b = *(const short8*)(Kh + (size_t)(nt * 16 + fr) * ldkv + kc + fk);
            s[nt] = __builtin_amdgcn_mfma_f32_16x16x32_bf16(a, b, s[nt], 0, 0, 0);
        }
    }

    float rmax[4] = {-INFINITY, -INFINITY, -INFINITY, -INFINITY};
#pragma unroll
    for (int nt = 0; nt < 16; ++nt)
#pragma unroll
        for (int rg = 0; rg < 4; ++rg) rmax[rg] = fmaxf(rmax[rg], s[nt][rg]);
#pragma unroll
    for (int d = 1; d < 16; d <<= 1)
#pragma unroll
        for (int rg = 0; rg < 4; ++rg)
            rmax[rg] = fmaxf(rmax[rg], __shfl_xor(rmax[rg], d));

    float rsum[4] = {0.f, 0.f, 0.f, 0.f};
#pragma unroll
    for (int nt = 0; nt < 16; ++nt) {
#pragma unroll
        for (int rg = 0; rg < 4; ++rg) {
            float p = __expf((s[nt][rg] - rmax[rg]) * 0.125f);
            rsum[rg] += p;
            sh.P[(m0 + q * 4 + rg) * PLD + nt * 16 + fr] = f2bf(p);
        }
    }
#pragma unroll
    for (int d = 1; d < 16; d <<= 1)
#pragma unroll
        for (int rg = 0; rg < 4; ++rg) rsum[rg] += __shfl_xor(rsum[rg], d);
    if (fr == 0) {
#pragma unroll
        for (int rg = 0; rg < 4; ++rg) sh.l[m0 + q * 4 + rg] = rsum[rg];
    }
    __syncthreads();

    floatx4 o[4];
#pragma unroll
    for (int i = 0; i < 4; ++i) o[i] = (floatx4){0.f, 0.f, 0.f, 0.f};

#pragma unroll
    for (int half = 0; half < 2; ++half) {
        {
            int r = tid & 127, cp = tid >> 7;
            const ushort_t* vrow = Vh + (size_t)(half * 128 + r) * ldkv + cp * 32;
#pragma unroll
            for (int c = 0; c < 4; ++c) {
                uint4 pk = *(const uint4*)(vrow + c * 8);
                int d0 = cp * 32 + c * 8;
                sh.VT[(d0 + 0) * VLD + r] = (ushort_t)(pk.x & 0xffff);
                sh.VT[(d0 + 1) * VLD + r] = (ushort_t)(pk.x >> 16);
                sh.VT[(d0 + 2) * VLD + r] = (ushort_t)(pk.y & 0xffff);
                sh.VT[(d0 + 3) * VLD + r] = (ushort_t)(pk.y >> 16);
                sh.VT[(d0 + 4) * VLD + r] = (ushort_t)(pk.z & 0xffff);
                sh.VT[(d0 + 5) * VLD + r] = (ushort_t)(pk.z >> 16);
                sh.VT[(d0 + 6) * VLD + r] = (ushort_t)(pk.w & 0xffff);
                sh.VT[(d0 + 7) * VLD + r] = (ushort_t)(pk.w >> 16);
            }
        }
        __syncthreads();
#pragma unroll
        for (int ks = 0; ks < 4; ++ks) {
            short8 a = *(const short8*)&sh.P[(m0 + fr) * PLD + half * 128 + ks * 32 + fk];
#pragma unroll
            for (int nt2 = 0; nt2 < 4; ++nt2) {
                short8 b = *(const short8*)&sh.VT[(nt2 * 16 + fr) * VLD + ks * 32 + fk];
                o[nt2] = __builtin_amdgcn_mfma_f32_16x16x32_bf16(a, b, o[nt2], 0, 0, 0);
            }
        }
        __syncthreads();
    }

    float linv[4];
#pragma unroll
    for (int rg = 0; rg < 4; ++rg) linv[rg] = 1.f / sh.l[m0 + q * 4 + rg];
#pragma unroll
    for (int nt2 = 0; nt2 < 4; ++nt2)
#pragma unroll
        for (int rg = 0; rg < 4; ++rg) {
            int row = rs * 64 + m0 + q * 4 + rg;
            O[(size_t)row * ldo + h * 64 + nt2 * 16 + fr] =
                f2bf(o[nt2][rg] * linv[rg]);
        }
}

// ===========================================================================
// Cooperative phase-2 kernel (fused weights).
// Grid 32 WGs x 512 thr (8 waves). WG = (head h = wg>>1, row-half rs2 = wg&1).
// Per step i:
//   KV_i = A @ Wsel^T + bsel  (A = AO[(i-1)&1], Wsel = Wc; i==1: A = x0,
//   Wsel = Wkv) -> LDS (K + V^T). Wave w builds keys [w*32, w*32+32).
//   __syncthreads -> attn rows [rs2*128, +128) (wave w: 16 rows) ->
//   AO[i&1] via write-through stores -> ONE grid barrier.
// Final out-proj (cum = AO_239 @ Wo^T + bo) runs as a separate GEMM after.
// ===========================================================================
#define KLD 72    // K stride (144 B)
#define TLD 264   // Vt / P stride (528 B)

__global__ __launch_bounds__(512, 1) void scan_coop_k(
    const ushort_t* __restrict__ Qchunk, int i0, int w0, int nsteps,
    const ushort_t* __restrict__ x0, ushort_t* __restrict__ AOb,
    const ushort_t* __restrict__ Wkv, const float* __restrict__ bkv,
    const ushort_t* __restrict__ Wc, const float* __restrict__ bc,
    unsigned* __restrict__ bar, unsigned s0)
{
    __shared__ ushort_t Kl[256 * KLD];
    __shared__ ushort_t Vt[64 * TLD];
    __shared__ ushort_t P[128 * TLD];
    const int wg = blockIdx.x, tid = threadIdx.x;
    const int h = wg >> 1, rs2 = wg & 1;
    const int wave = tid >> 6, lane = tid & 63;
    const int fr = lane & 15, q = lane >> 4, fk = q * 8;
    const int g = wg & 3;

    unsigned s = s0;
    for (int t = 0; t < nsteps; ++t, ++s) {
        const int i = i0 + t;
        const ushort_t* Asrc;
        const ushort_t* Wsel;
        const float* bsel;
        if (i == 1) { Asrc = x0; Wsel = Wkv; bsel = bkv; }
        else { Asrc = AOb + (size_t)((i - 1) & 1) * WIN; Wsel = Wc; bsel = bc; }

        // ---------- KV build: wave w -> keys [w*32, w*32+32) ----------
        {
            floatx4 acc[2][8];
#pragma unroll
            for (int mt = 0; mt < 2; ++mt)
#pragma unroll
                for (int nt = 0; nt < 8; ++nt)
                    acc[mt][nt] = (floatx4){0.f, 0.f, 0.f, 0.f};
            const ushort_t* arow = Asrc + (size_t)(wave * 32 + fr) * 1024 + fk;
            const ushort_t* wrow[8];
#pragma unroll
            for (int nt = 0; nt < 8; ++nt) {
                int n = ((nt >> 2) << 10) + h * 64 + (nt & 3) * 16 + fr;
                wrow[nt] = Wsel + (size_t)n * 1024 + fk;
            }
            for (int k0 = 0; k0 < 1024; k0 += 32) {
                short8 a0 = ld16_sys(arow + k0);
                short8 a1 = ld16_sys(arow + (size_t)16 * 1024 + k0);
#pragma unroll
                for (int nt = 0; nt < 8; ++nt) {
                    short8 b = *(const short8*)(wrow[nt] + k0);
                    acc[0][nt] = __builtin_amdgcn_mfma_f32_16x16x32_bf16(
                        a0, b, acc[0][nt], 0, 0, 0);
                    acc[1][nt] = __builtin_amdgcn_mfma_f32_16x16x32_bf16(
                        a1, b, acc[1][nt], 0, 0, 0);
                }
            }
#pragma unroll
            for (int mt = 0; mt < 2; ++mt) {
                const int kb = wave * 32 + mt * 16;
#pragma unroll
                for (int nt = 0; nt < 4; ++nt) {
                    float bzk = bsel[h * 64 + nt * 16 + fr];
#pragma unroll
                    for (int rg = 0; rg < 4; ++rg)
                        Kl[(kb + q * 4 + rg) * KLD + nt * 16 + fr] =
                            f2bf(acc[mt][nt][rg] + bzk);
                    float bzv = bsel[1024 + h * 64 + nt * 16 + fr];
                    ushort4 pv;
                    pv.x = f2bf(acc[mt][nt + 4][0] + bzv);
                    pv.y = f2bf(acc[mt][nt + 4][1] + bzv);
                    pv.z = f2bf(acc[mt][nt + 4][2] + bzv);
                    pv.w = f2bf(acc[mt][nt + 4][3] + bzv);
                    *(ushort4*)&Vt[(nt * 16 + fr) * TLD + kb + q * 4] = pv;
                }
            }
        }
        __syncthreads();

        // ---------- attention: wave w -> rows rs2*128 + w*16 .. +16 ----------
        ushort_t* AOcur = AOb + (size_t)(i & 1) * WIN;
        {
            const int m0g = rs2 * 128 + wave * 16;   // global Q row base
            const int pl0 = wave * 16;               // local P row base
            const ushort_t* Qrow = Qchunk + (size_t)(i - w0) * WIN
                + (size_t)(m0g + fr) * 1024 + h * 64;
            floatx4 sc[16];
#pragma unroll
            for (int nt = 0; nt < 16; ++nt) sc[nt] = (floatx4){0.f, 0.f, 0.f, 0.f};
#pragma unroll
            for (int kc = 0; kc < 64; kc += 32) {
                short8 a = *(const short8*)(Qrow + kc);
#pragma unroll
                for (int nt = 0; nt < 16; ++nt) {
                    short8 b = *(const short8*)&Kl[(nt * 16 + fr) * KLD + kc + fk];
                    sc[nt] = __builtin_amdgcn_mfma_f32_16x16x32_bf16(
                        a, b, sc[nt], 0, 0, 0);
                }
            }
            float rmax[4] = {-INFINITY, -INFINITY, -INFINITY, -INFINITY};
#pragma unroll
            for (int nt = 0; nt < 16; ++nt)
#pragma unroll
                for (int rg = 0; rg < 4; ++rg) rmax[rg] = fmaxf(rmax[rg], sc[nt][rg]);
#pragma unroll
            for (int d = 1; d < 16; d <<= 1)
#pragma unroll
                for (int rg = 0; rg < 4; ++rg)
                    rmax[rg] = fmaxf(rmax[rg], __shfl_xor(rmax[rg], d));
            float rsum[4] = {0.f, 0.f, 0.f, 0.f};
#pragma unroll
            for (int nt = 0; nt < 16; ++nt) {
#pragma unroll
                for (int rg = 0; rg < 4; ++rg) {
                    float p = __expf((sc[nt][rg] - rmax[rg]) * 0.125f);
                    rsum[rg] += p;
                    P[(pl0 + q * 4 + rg) * TLD + nt * 16 + fr] = f2bf(p);
                }
            }
#pragma unroll
            for (int d = 1; d < 16; d <<= 1)
#pragma unroll
                for (int rg = 0; rg < 4; ++rg) rsum[rg] += __shfl_xor(rsum[rg], d);

            floatx4 o[4];
#pragma unroll
            for (int nt = 0; nt < 4; ++nt) o[nt] = (floatx4){0.f, 0.f, 0.f, 0.f};
#pragma unroll
            for (int kt = 0; kt < 8; ++kt) {
                short8 a = *(const short8*)&P[(pl0 + fr) * TLD + kt * 32 + fk];
#pragma unroll
                for (int nt = 0; nt < 4; ++nt) {
                    short8 b = *(const short8*)&Vt[(nt * 16 + fr) * TLD + kt * 32 + fk];
                    o[nt] = __builtin_amdgcn_mfma_f32_16x16x32_bf16(
                        a, b, o[nt], 0, 0, 0);
                }
            }
            float linv[4];
#pragma unroll
            for (int rg = 0; rg < 4; ++rg) linv[rg] = 1.f / rsum[rg];
#pragma unroll
            for (int nt = 0; nt < 4; ++nt)
#pragma unroll
                for (int rg = 0; rg < 4; ++rg) {
                    int row = m0g + q * 4 + rg;
                    st2_wt(AOcur + (size_t)row * 1024 + h * 64 + nt * 16 + fr,
                           f2bf(o[nt][rg] * linv[rg]));
                }
        }
        grid_bar(bar, g, s);   // AO_i complete
    }
}

// ---------------------------------------------------------------------------
extern "C" void kernel_launch(void* const* d_in, const int* in_sizes, int n_in,
                              void* d_out, int out_size, void* d_ws, size_t ws_size,
                              hipStream_t stream)
{
    const float* path   = (const float*)d_in[0];
    const float* w_in1  = (const float*)d_in[1];
    const float* b_in1  = (const float*)d_in[2];
    const float* w_out1 = (const float*)d_in[3];
    const float* b_out1 = (const float*)d_in[4];
    const float* w_lin  = (const float*)d_in[5];
    const float* b_lin  = (const float*)d_in[6];
    const float* w_in2  = (const float*)d_in[7];
    const float* b_in2  = (const float*)d_in[8];
    const float* w_out2 = (const float*)d_in[9];
    const float* b_out2 = (const float*)d_in[10];
    float* out = (float*)d_out;

    // workspace: barriers/bias (16 KB) then bf16 buffers (~58 MB)
    unsigned* bar = (unsigned*)d_ws;                      // 8 KB
    float* bc      = (float*)d_ws + 2048;                 // 2048 fp32
    float* zerosf  = bc + 2048;                           // 1024 fp32
    ushort_t* ws = (ushort_t*)d_ws + 16384;
    ushort_t* path_bf  = ws;                              // 4096*1024
    ushort_t* w_in1_bf = path_bf  + (size_t)4096 * 1024;  // 3072*1024
    ushort_t* w_out1_bf= w_in1_bf + (size_t)3072 * 1024;
    ushort_t* w_lin_bf = w_out1_bf+ (size_t)1024 * 1024;
    ushort_t* w_in2_bf = w_lin_bf + (size_t)1024 * 1024;  // 3072*1024
    ushort_t* w_out2_bf= w_in2_bf + (size_t)3072 * 1024;
    ushort_t* WoT_bf   = w_out2_bf+ (size_t)1024 * 1024;  // 1024*1024
    ushort_t* Wc_bf    = WoT_bf   + (size_t)1024 * 1024;  // 2048*1024
    ushort_t* qkv_bf   = Wc_bf    + (size_t)2048 * 1024;  // 2048*3072
    ushort_t* ybuf_bf  = qkv_bf;                          // alias (qkv dead)
    ushort_t* ao_bf    = qkv_bf   + (size_t)2048 * 3072;  // 2048*1024
    ushort_t* Xchunk   = ao_bf    + (size_t)2048 * 1024;  // 2048*1024
    ushort_t* Qchunk   = Xchunk   + (size_t)2048 * 1024;  // 2048*1024
    ushort_t* AOb      = Qchunk   + (size_t)2048 * 1024;  // 2 x 256*1024
    ushort_t* x0buf    = AOb + 2 * WIN;                   // 256*1024
    ushort_t* dummy    = x0buf + WIN;                     // 256*1024

    hipMemsetAsync(bar, 0, 8192, stream);
    hipMemsetAsync(zerosf, 0, 1024 * sizeof(float), stream);

    cast_bf_k<<<4096, 256, 0, stream>>>(path,  path_bf,  4096 * 1024);
    cast_bf_k<<<3072, 256, 0, stream>>>(w_in1, w_in1_bf, 3072 * 1024);
    cast_bf_k<<<1024, 256, 0, stream>>>(w_out1, w_out1_bf, 1024 * 1024);
    cast_bf_k<<<1024, 256, 0, stream>>>(w_lin, w_lin_bf, 1024 * 1024);
    cast_bf_k<<<3072, 256, 0, stream>>>(w_in2, w_in2_bf, 3072 * 1024);
    cast_bf_k<<<1024, 256, 0, stream>>>(w_out2, w_out2_bf, 1024 * 1024);

    // fused scan weights: Wc = Wkv @ Wo  (bf16), bc = bkv + Wkv @ bo (fp32)
    transpose_k<<<dim3(16, 16), 256, 0, stream>>>(w_out2_bf, WoT_bf);
    bc_k<<<8, 256, 0, stream>>>(w_in2, b_in2, b_out2, bc);
    gemm_bf_k<<<dim3(8, 16), 256, 0, stream>>>(
        w_in2_bf + (size_t)1024 * 1024, 1024, WoT_bf, zerosf,
        Wc_bf, nullptr, 1024, 1024, 0);

    unsigned sbase = 1;
    for (int c = 0; c < NCHUNK; ++c) {
        int w0 = c * CHUNK;
        // ---- Phase 1 for windows [w0, w0+CHUNK) ----
        gemm_qkv_k<<<dim3(24, 16), 256, 0, stream>>>(
            path_bf, w_in1_bf, b_in1, qkv_bf, w0);
        attn_mfma_k<<<dim3(4, NH, CHUNK), 256, 0, stream>>>(qkv_bf, ao_bf);
        gemm_bf_k<<<dim3(8, 16), 256, 0, stream>>>(
            ao_bf, 1024, w_out1_bf, b_out1, ybuf_bf, nullptr, 1024, 1024, 0);
        gemm_bf_k<<<dim3(8, 16), 256, 0, stream>>>(
            ybuf_bf, 1024, w_lin_bf, b_lin, Xchunk, nullptr, 1024, 1024, 1);
        // Q for the whole chunk (rows 0..1023 of w_in2 are wq)
        gemm_bf_k<<<dim3(8, 16), 256, 0, stream>>>(
            Xchunk, 1024, w_in2_bf, b_in2, Qchunk, nullptr, 1024, 1024, 0);

        // ---- Phase 2: one cooperative launch per chunk ----
        if (c == 0) {
            hipMemcpyAsync(x0buf, Xchunk, WIN * sizeof(ushort_t),
                           hipMemcpyDeviceToDevice, stream);
        }
        int i0 = (c == 0) ? 1 : w0;
        int nsteps = (c == 0) ? CHUNK - 1 : CHUNK;
        const ushort_t* QchunkP = Qchunk;
        const ushort_t* x0P = x0buf;
        ushort_t* AObP = AOb;
        const ushort_t* WkvP = w_in2_bf + (size_t)1024 * 1024;
        const float* bkvP = b_in2 + 1024;
        const ushort_t* WcP = Wc_bf;
        const float* bcP = bc;
        unsigned* barP = bar;
        unsigned sb = sbase;
        void* args[] = {&QchunkP, &i0, &w0, &nsteps, &x0P, &AObP,
                        &WkvP, &bkvP, &WcP, &bcP, &barP, &sb};
        hipLaunchCooperativeKernel((void*)scan_coop_k, dim3(32), dim3(512),
                                   args, 0, stream);
        sbase += (unsigned)nsteps;
    }

    // final out-projection: out = AO_239 @ Wo^T + bo  (fp32 to d_out)
    gemm_bf_k<<<dim3(8, 2), 256, 0, stream>>>(
        AOb + (size_t)((N_WIN - 1) & 1) * WIN, 1024, w_out2_bf, b_out2,
        dummy, out, 1024, 1024, 0);
}

// Round 11
// 21916.936 us; speedup vs baseline: 1.1935x; 1.1935x over previous
//
#include <hip/hip_runtime.h>
#include <math.h>

// Problem constants
#define D_MODEL 1024
#define N_WIN   240
#define TOK     256
#define NH      16
#define DH      64
#define CHUNK   8
#define NCHUNK  30
#define WIN     ((size_t)TOK * D_MODEL)

typedef unsigned short ushort_t;
typedef unsigned long long ull_t;
typedef __attribute__((ext_vector_type(8))) short short8;
typedef __attribute__((ext_vector_type(4))) float floatx4;

__device__ __forceinline__ ushort_t f2bf(float f) {   // RNE
    unsigned u = __float_as_uint(f);
    unsigned lsb = (u >> 16) & 1u;
    u += 0x7fffu + lsb;
    return (ushort_t)(u >> 16);
}

// ---------------------------------------------------------------------------
// Coherence primitives (round-9 proven):
//  - st2_wt: 2B write-through store (lands at coherence point / IC).
//  - ld8_sys/ld16_sys: system-scope relaxed loads (bypass L1/L2, IC-fresh,
//    vmcnt-pipelined). Used ONLY for the AO scan buffers.
//  - No cache invalidation anywhere -> weights/Q stay L2-hot across steps.
// ---------------------------------------------------------------------------
__device__ __forceinline__ void st2_wt(ushort_t* p, ushort_t v) {
    unsigned vv = v;
    asm volatile("global_store_short %0, %1, off sc1"
                 :: "v"(p), "v"(vv) : "memory");
}
__device__ __forceinline__ void rel_drain() {
    asm volatile("s_waitcnt vmcnt(0)" ::: "memory");
}
__device__ __forceinline__ ull_t ld8_sys(const ushort_t* p) {
    return __hip_atomic_load((const ull_t*)p, __ATOMIC_RELAXED,
                             __HIP_MEMORY_SCOPE_SYSTEM);
}
__device__ __forceinline__ short8 ld16_sys(const ushort_t* p) {
    union { ull_t u[2]; short8 s; } c;
    c.u[0] = ld8_sys(p); c.u[1] = ld8_sys(p + 4);
    return c.s;
}

// async global->LDS, 16B per lane (phase-1 GEMM staging)
#define GLDS(g, l) __builtin_amdgcn_global_load_lds( \
    (const __attribute__((address_space(1))) unsigned int*)(g), \
    (__attribute__((address_space(3))) unsigned int*)(l), 16, 0, 0)

// ---------------------------------------------------------------------------
// Grid barrier (tree, fence-free): all threads drain stores, WG syncs, tid0
// signals agent-scope counters and spins on release. 8 subs x 8 arrivals.
// ---------------------------------------------------------------------------
__device__ __forceinline__ void grid_bar(unsigned* base, int g, unsigned s)
{
    rel_drain();
    __syncthreads();
    if (threadIdx.x == 0) {
        unsigned old = __hip_atomic_fetch_add(base + g * 32, 1u,
                __ATOMIC_RELAXED, __HIP_MEMORY_SCOPE_AGENT);
        if (old == 8u * s - 1u) {
            unsigned r = __hip_atomic_fetch_add(base + 256, 1u,
                    __ATOMIC_RELAXED, __HIP_MEMORY_SCOPE_AGENT);
            if (r == 8u * s - 1u)
                __hip_atomic_store(base + 288, s, __ATOMIC_RELAXED,
                                   __HIP_MEMORY_SCOPE_AGENT);
        }
        while (__hip_atomic_load(base + 288, __ATOMIC_RELAXED,
                                 __HIP_MEMORY_SCOPE_AGENT) < s)
            __builtin_amdgcn_s_sleep(1);
    }
    __syncthreads();
}

// ---------------------------------------------------------------------------
// fp32 -> bf16 cast
// ---------------------------------------------------------------------------
__global__ __launch_bounds__(256) void cast_bf_k(
    const float* __restrict__ s, ushort_t* __restrict__ d, int n)
{
    int i = (blockIdx.x * 256 + threadIdx.x) * 4;
    if (i >= n) return;
    float4 v = *(const float4*)(s + i);
    ushort4 o;
    o.x = f2bf(v.x); o.y = f2bf(v.y); o.z = f2bf(v.z); o.w = f2bf(v.w);
    *(ushort4*)(d + i) = o;
}

// 64x64-tile bf16 transpose: dst[c][r] = src[r][c], both 1024x1024
__global__ __launch_bounds__(256) void transpose_k(
    const ushort_t* __restrict__ src, ushort_t* __restrict__ dst)
{
    __shared__ ushort_t t[64][65];
    const int bx = blockIdx.x * 64, by = blockIdx.y * 64;
    const int c = threadIdx.x & 63, r0 = threadIdx.x >> 6;
#pragma unroll
    for (int k = 0; k < 16; ++k) {
        int r = r0 + k * 4;
        t[r][c] = src[(size_t)(by + r) * 1024 + bx + c];
    }
    __syncthreads();
#pragma unroll
    for (int k = 0; k < 16; ++k) {
        int r = r0 + k * 4;
        dst[(size_t)(bx + r) * 1024 + by + c] = t[c][r];
    }
}

// bc[n] = b_in2[1024+n] + dot(w_in2 row (1024+n), b_out2), fp32, n in [0,2048)
__global__ __launch_bounds__(256) void bc_k(
    const float* __restrict__ w_in2, const float* __restrict__ b_in2,
    const float* __restrict__ b_out2, float* __restrict__ bc)
{
    int n = blockIdx.x * 256 + threadIdx.x;
    const float* row = w_in2 + (size_t)(1024 + n) * 1024;
    float s = b_in2[1024 + n];
    for (int j = 0; j < 1024; j += 4) {
        float4 w = *(const float4*)(row + j);
        float4 b = *(const float4*)(b_out2 + j);
        s += w.x * b.x + w.y * b.y + w.z * b.z + w.w * b.w;
    }
    bc[n] = s;
}

// ---------------------------------------------------------------------------
// Phase-1 bf16 MFMA GEMM core (m97 structure), 128x128 tile, BK=32.
// ---------------------------------------------------------------------------
template<bool GATHER>
__device__ __forceinline__ void gemm_core(
    const ushort_t* __restrict__ A, int lda, int w0,
    const ushort_t* __restrict__ W, const float* __restrict__ bias,
    ushort_t* __restrict__ Cb, float* __restrict__ Cf, int ldc,
    int K, int m0, int n0, int co, int relu)
{
    __shared__ ushort_t As[128 * 32];
    __shared__ ushort_t Bs[128 * 32];
    const int tid = threadIdx.x;
    const int wave = tid >> 6, lane = tid & 63;
    const int wm = wave & 1, wn = wave >> 1;

    int r0 = m0 + (tid >> 2), r1 = r0 + 64;
    if (GATHER) {
        r0 = (w0 + (r0 >> 8)) * 16 + (r0 & 255);
        r1 = (w0 + (r1 >> 8)) * 16 + (r1 & 255);
    }
    const int kcol = (tid & 3) * 8;
    const ushort_t* gA0 = A + (size_t)r0 * lda + kcol;
    const ushort_t* gA1 = A + (size_t)r1 * lda + kcol;
    const ushort_t* pW  = W + (size_t)n0 * K;
    const ushort_t* gB0 = pW + (size_t)(tid >> 2) * K + kcol;
    const ushort_t* gB1 = gB0 + (size_t)64 * K;
    ushort_t* lA = As + wave * 512;
    ushort_t* lB = Bs + wave * 512;

    floatx4 acc[4][4];
#pragma unroll
    for (int i = 0; i < 4; ++i)
#pragma unroll
        for (int j = 0; j < 4; ++j) acc[i][j] = (floatx4){0.f, 0.f, 0.f, 0.f};

    const int fr = lane & 15, fk = (lane >> 4) * 8;
    const int arow = (wm * 64 + fr) * 32 + fk;
    const int brow = (wn * 64 + fr) * 32 + fk;

    for (int k0 = 0; k0 < K; k0 += 32) {
        GLDS(gA0 + k0, lA);
        GLDS(gA1 + k0, lA + 2048);
        GLDS(gB0 + k0, lB);
        GLDS(gB1 + k0, lB + 2048);
        __syncthreads();
        short8 a[4], b[4];
#pragma unroll
        for (int mi = 0; mi < 4; ++mi) a[mi] = *(const short8*)&As[arow + mi * 512];
#pragma unroll
        for (int ni = 0; ni < 4; ++ni) b[ni] = *(const short8*)&Bs[brow + ni * 512];
#pragma unroll
        for (int mi = 0; mi < 4; ++mi)
#pragma unroll
            for (int ni = 0; ni < 4; ++ni)
                acc[mi][ni] = __builtin_amdgcn_mfma_f32_16x16x32_bf16(
                    a[mi], b[ni], acc[mi][ni], 0, 0, 0);
        __syncthreads();
    }

    const int crq = (lane >> 4) * 4;
    const int ccol = lane & 15;
#pragma unroll
    for (int mi = 0; mi < 4; ++mi) {
#pragma unroll
        for (int ni = 0; ni < 4; ++ni) {
            int lc = wn * 64 + ni * 16 + ccol;
            float bz = bias[n0 + lc];
#pragma unroll
            for (int rg = 0; rg < 4; ++rg) {
                int row = m0 + wm * 64 + mi * 16 + crq + rg;
                float v = acc[mi][ni][rg] + bz;
                if (relu) v = fmaxf(v, 0.f);
                size_t off = (size_t)row * ldc + co + lc;
                if (Cb) Cb[off] = f2bf(v);
                if (Cf) Cf[off] = v;
            }
        }
    }
}

__global__ __launch_bounds__(256) void gemm_bf_k(
    const ushort_t* __restrict__ A, int lda,
    const ushort_t* __restrict__ W, const float* __restrict__ bias,
    ushort_t* __restrict__ Cb, float* __restrict__ Cf, int ldc,
    int K, int relu)
{
    gemm_core<false>(A, lda, 0, W, bias, Cb, Cf, ldc, K,
                     blockIdx.y * 128, blockIdx.x * 128, blockIdx.x * 128, relu);
}

__global__ __launch_bounds__(256) void gemm_qkv_k(
    const ushort_t* __restrict__ path_bf, const ushort_t* __restrict__ W,
    const float* __restrict__ bias, ushort_t* __restrict__ Cb, int w0)
{
    gemm_core<true>(path_bf, 1024, w0, W, bias, Cb, nullptr, 3072, 1024,
                    blockIdx.y * 128, blockIdx.x * 128, blockIdx.x * 128, 0);
}

// ---------------------------------------------------------------------------
// Phase-1 MFMA attention (unchanged).
// ---------------------------------------------------------------------------
#define PLD 260
#define VLD 132

struct AttnShared {
    ushort_t P[64 * PLD];
    ushort_t VT[64 * VLD];
    float    l[64];
};

__global__ __launch_bounds__(256) void attn_mfma_k(
    const ushort_t* __restrict__ qkv, ushort_t* __restrict__ ao)
{
    __shared__ AttnShared sh;
    const int rs = blockIdx.x, h = blockIdx.y, b = blockIdx.z;
    const ushort_t* base = qkv + (size_t)b * TOK * 3072;
    const ushort_t* Q = base;
    const ushort_t* K = base + 1024;
    const ushort_t* V = base + 2048;
    ushort_t* O = ao + (size_t)b * TOK * 1024;
    const int ldq = 3072, ldkv = 3072, ldo = 1024;
    const int tid = threadIdx.x;
    const int wave = tid >> 6, lane = tid & 63;
    const int fr = lane & 15, q = lane >> 4, fk = q * 8;
    const ushort_t* Qh = Q + (size_t)(rs * 64) * ldq + h * 64;
    const ushort_t* Kh = K + h * 64;
    const ushort_t* Vh = V + h * 64;
    const int m0 = wave * 16;

    floatx4 s[16];
#pragma unroll
    for (int nt = 0; nt < 16; ++nt) s[nt] = (floatx4){0.f, 0.f, 0.f, 0.f};
#pragma unroll
    for (int kc = 0; kc < 64; kc += 32) {
        short8 a = *(const short8*)(Qh + (size_t)(m0 + fr) * ldq + kc + fk);
#pragma unroll
        for (int nt = 0; nt < 16; ++nt) {
            short8 b = *(const short8*)(Kh + (size_t)(nt * 16 + fr) * ldkv + kc + fk);
            s[nt] = __builtin_amdgcn_mfma_f32_16x16x32_bf16(a, b, s[nt], 0, 0, 0);
        }
    }

    float rmax[4] = {-INFINITY, -INFINITY, -INFINITY, -INFINITY};
#pragma unroll
    for (int nt = 0; nt < 16; ++nt)
#pragma unroll
        for (int rg = 0; rg < 4; ++rg) rmax[rg] = fmaxf(rmax[rg], s[nt][rg]);
#pragma unroll
    for (int d = 1; d < 16; d <<= 1)
#pragma unroll
        for (int rg = 0; rg < 4; ++rg)
            rmax[rg] = fmaxf(rmax[rg], __shfl_xor(rmax[rg], d));

    float rsum[4] = {0.f, 0.f, 0.f, 0.f};
#pragma unroll
    for (int nt = 0; nt < 16; ++nt) {
#pragma unroll
        for (int rg = 0; rg < 4; ++rg) {
            float p = __expf((s[nt][rg] - rmax[rg]) * 0.125f);
            rsum[rg] += p;
            sh.P[(m0 + q * 4 + rg) * PLD + nt * 16 + fr] = f2bf(p);
        }
    }
#pragma unroll
    for (int d = 1; d < 16; d <<= 1)
#pragma unroll
        for (int rg = 0; rg < 4; ++rg) rsum[rg] += __shfl_xor(rsum[rg], d);
    if (fr == 0) {
#pragma unroll
        for (int rg = 0; rg < 4; ++rg) sh.l[m0 + q * 4 + rg] = rsum[rg];
    }
    __syncthreads();

    floatx4 o[4];
#pragma unroll
    for (int i = 0; i < 4; ++i) o[i] = (floatx4){0.f, 0.f, 0.f, 0.f};

#pragma unroll
    for (int half = 0; half < 2; ++half) {
        {
            int r = tid & 127, cp = tid >> 7;
            const ushort_t* vrow = Vh + (size_t)(half * 128 + r) * ldkv + cp * 32;
#pragma unroll
            for (int c = 0; c < 4; ++c) {
                uint4 pk = *(const uint4*)(vrow + c * 8);
                int d0 = cp * 32 + c * 8;
                sh.VT[(d0 + 0) * VLD + r] = (ushort_t)(pk.x & 0xffff);
                sh.VT[(d0 + 1) * VLD + r] = (ushort_t)(pk.x >> 16);
                sh.VT[(d0 + 2) * VLD + r] = (ushort_t)(pk.y & 0xffff);
                sh.VT[(d0 + 3) * VLD + r] = (ushort_t)(pk.y >> 16);
                sh.VT[(d0 + 4) * VLD + r] = (ushort_t)(pk.z & 0xffff);
                sh.VT[(d0 + 5) * VLD + r] = (ushort_t)(pk.z >> 16);
                sh.VT[(d0 + 6) * VLD + r] = (ushort_t)(pk.w & 0xffff);
                sh.VT[(d0 + 7) * VLD + r] = (ushort_t)(pk.w >> 16);
            }
        }
        __syncthreads();
#pragma unroll
        for (int ks = 0; ks < 4; ++ks) {
            short8 a = *(const short8*)&sh.P[(m0 + fr) * PLD + half * 128 + ks * 32 + fk];
#pragma unroll
            for (int nt2 = 0; nt2 < 4; ++nt2) {
                short8 b = *(const short8*)&sh.VT[(nt2 * 16 + fr) * VLD + ks * 32 + fk];
                o[nt2] = __builtin_amdgcn_mfma_f32_16x16x32_bf16(a, b, o[nt2], 0, 0, 0);
            }
        }
        __syncthreads();
    }

    float linv[4];
#pragma unroll
    for (int rg = 0; rg < 4; ++rg) linv[rg] = 1.f / sh.l[m0 + q * 4 + rg];
#pragma unroll
    for (int nt2 = 0; nt2 < 4; ++nt2)
#pragma unroll
        for (int rg = 0; rg < 4; ++rg) {
            int row = rs * 64 + m0 + q * 4 + rg;
            O[(size_t)row * ldo + h * 64 + nt2 * 16 + fr] =
                f2bf(o[nt2][rg] * linv[rg]);
        }
}

// ===========================================================================
// Cooperative phase-2 kernel: round-9 layout + fused weights + 1 barrier.
// Grid 64 WGs x 256 thr. WG = (head h = wg>>2, row-slice rs = wg&3).
// Per step i:
//   KV_i = A @ Wsel^T + bsel (A = AO[(i-1)&1] via ld16_sys, 2-iter prefetch;
//   i==1: A = x0, Wsel = Wkv). Wave w builds keys [w*64, +64) -> LDS
//   (K row-major + V transposed). __syncthreads.
//   attn rows [rs*64, +64) (wave w: 16 rows) -> AO[i&1] via st2_wt.
//   ONE grid barrier. Final out-proj runs as a plain GEMM after all chunks.
// ===========================================================================
#define KLD 72    // K stride (144 B)
#define TLD 264   // Vt / P stride (528 B)

__global__ __launch_bounds__(256, 1) void scan_coop_k(
    const ushort_t* __restrict__ Qchunk, int i0, int w0, int nsteps,
    const ushort_t* __restrict__ x0, ushort_t* __restrict__ AOb,
    const ushort_t* __restrict__ Wkv, const float* __restrict__ bkv,
    const ushort_t* __restrict__ Wc, const float* __restrict__ bc,
    unsigned* __restrict__ bar, unsigned s0)
{
    __shared__ ushort_t Kl[256 * KLD];
    __shared__ ushort_t Vt[64 * TLD];
    __shared__ ushort_t P[64 * TLD];
    const int wg = blockIdx.x, tid = threadIdx.x;
    const int h = wg >> 2, rs = wg & 3;
    const int wave = tid >> 6, lane = tid & 63;
    const int fr = lane & 15, q = lane >> 4, fk = q * 8;
    const int g = wg & 7;

    unsigned s = s0;
    for (int t = 0; t < nsteps; ++t, ++s) {
        const int i = i0 + t;
        const ushort_t* Asrc;
        const ushort_t* Wsel;
        const float* bsel;
        if (i == 1) { Asrc = x0; Wsel = Wkv; bsel = bkv; }
        else { Asrc = AOb + (size_t)((i - 1) & 1) * WIN; Wsel = Wc; bsel = bc; }

        // ---------- KV build: wave w -> keys [w*64, w*64+64) ----------
        {
            floatx4 acc[4][8];
#pragma unroll
            for (int mt = 0; mt < 4; ++mt)
#pragma unroll
                for (int nt = 0; nt < 8; ++nt)
                    acc[mt][nt] = (floatx4){0.f, 0.f, 0.f, 0.f};
            const ushort_t* arow = Asrc + (size_t)(wave * 64 + fr) * 1024 + fk;
            const ushort_t* wrow[8];
#pragma unroll
            for (int nt = 0; nt < 8; ++nt) {
                int n = ((nt >> 2) << 10) + h * 64 + (nt & 3) * 16 + fr;
                wrow[nt] = Wsel + (size_t)n * 1024 + fk;
            }
            // 2-iteration register prefetch of the system-scope A loads
            short8 a0[4], a1[4];
#pragma unroll
            for (int mt = 0; mt < 4; ++mt)
                a0[mt] = ld16_sys(arow + (size_t)(mt * 16) * 1024);
#pragma unroll
            for (int mt = 0; mt < 4; ++mt)
                a1[mt] = ld16_sys(arow + (size_t)(mt * 16) * 1024 + 32);
            for (int k0 = 0; k0 < 1024; k0 += 64) {
                short8 a2[4], a3[4];
#pragma unroll
                for (int mt = 0; mt < 4; ++mt)   // overread past end is benign
                    a2[mt] = ld16_sys(arow + (size_t)(mt * 16) * 1024 + k0 + 64);
#pragma unroll
                for (int mt = 0; mt < 4; ++mt)
                    a3[mt] = ld16_sys(arow + (size_t)(mt * 16) * 1024 + k0 + 96);
#pragma unroll
                for (int nt = 0; nt < 8; ++nt) {
                    short8 b = *(const short8*)(wrow[nt] + k0);
#pragma unroll
                    for (int mt = 0; mt < 4; ++mt)
                        acc[mt][nt] = __builtin_amdgcn_mfma_f32_16x16x32_bf16(
                            a0[mt], b, acc[mt][nt], 0, 0, 0);
                }
#pragma unroll
                for (int nt = 0; nt < 8; ++nt) {
                    short8 b = *(const short8*)(wrow[nt] + k0 + 32);
#pragma unroll
                    for (int mt = 0; mt < 4; ++mt)
                        acc[mt][nt] = __builtin_amdgcn_mfma_f32_16x16x32_bf16(
                            a1[mt], b, acc[mt][nt], 0, 0, 0);
                }
#pragma unroll
                for (int mt = 0; mt < 4; ++mt) { a0[mt] = a2[mt]; a1[mt] = a3[mt]; }
            }
            // epilogue: K -> Kl[key][dim], V -> Vt[dim][key]
#pragma unroll
            for (int mt = 0; mt < 4; ++mt) {
                const int kb = wave * 64 + mt * 16;
#pragma unroll
                for (int nt = 0; nt < 4; ++nt) {
                    float bzk = bsel[h * 64 + nt * 16 + fr];
#pragma unroll
                    for (int rg = 0; rg < 4; ++rg)
                        Kl[(kb + q * 4 + rg) * KLD + nt * 16 + fr] =
                            f2bf(acc[mt][nt][rg] + bzk);
                    float bzv = bsel[1024 + h * 64 + nt * 16 + fr];
                    ushort4 pv;
                    pv.x = f2bf(acc[mt][nt + 4][0] + bzv);
                    pv.y = f2bf(acc[mt][nt + 4][1] + bzv);
                    pv.z = f2bf(acc[mt][nt + 4][2] + bzv);
                    pv.w = f2bf(acc[mt][nt + 4][3] + bzv);
                    *(ushort4*)&Vt[(nt * 16 + fr) * TLD + kb + q * 4] = pv;
                }
            }
        }
        __syncthreads();

        // ---------- attention: wave w -> rows rs*64 + w*16 .. +16 ----------
        ushort_t* AOcur = AOb + (size_t)(i & 1) * WIN;
        {
            const int m0g = rs * 64 + wave * 16;    // global Q row base
            const int pl0 = wave * 16;              // local P row base
            const ushort_t* Qrow = Qchunk + (size_t)(i - w0) * WIN
                + (size_t)(m0g + fr) * 1024 + h * 64;
            floatx4 sc[16];
#pragma unroll
            for (int nt = 0; nt < 16; ++nt) sc[nt] = (floatx4){0.f, 0.f, 0.f, 0.f};
#pragma unroll
            for (int kc = 0; kc < 64; kc += 32) {
                short8 a = *(const short8*)(Qrow + kc);
#pragma unroll
                for (int nt = 0; nt < 16; ++nt) {
                    short8 b = *(const short8*)&Kl[(nt * 16 + fr) * KLD + kc + fk];
                    sc[nt] = __builtin_amdgcn_mfma_f32_16x16x32_bf16(
                        a, b, sc[nt], 0, 0, 0);
                }
            }
            float rmax[4] = {-INFINITY, -INFINITY, -INFINITY, -INFINITY};
#pragma unroll
            for (int nt = 0; nt < 16; ++nt)
#pragma unroll
                for (int rg = 0; rg < 4; ++rg) rmax[rg] = fmaxf(rmax[rg], sc[nt][rg]);
#pragma unroll
            for (int d = 1; d < 16; d <<= 1)
#pragma unroll
                for (int rg = 0; rg < 4; ++rg)
                    rmax[rg] = fmaxf(rmax[rg], __shfl_xor(rmax[rg], d));
            float rsum[4] = {0.f, 0.f, 0.f, 0.f};
#pragma unroll
            for (int nt = 0; nt < 16; ++nt) {
#pragma unroll
                for (int rg = 0; rg < 4; ++rg) {
                    float p = __expf((sc[nt][rg] - rmax[rg]) * 0.125f);
                    rsum[rg] += p;
                    P[(pl0 + q * 4 + rg) * TLD + nt * 16 + fr] = f2bf(p);
                }
            }
#pragma unroll
            for (int d = 1; d < 16; d <<= 1)
#pragma unroll
                for (int rg = 0; rg < 4; ++rg) rsum[rg] += __shfl_xor(rsum[rg], d);

            floatx4 o[4];
#pragma unroll
            for (int nt = 0; nt < 4; ++nt) o[nt] = (floatx4){0.f, 0.f, 0.f, 0.f};
#pragma unroll
            for (int kt = 0; kt < 8; ++kt) {
                short8 a = *(const short8*)&P[(pl0 + fr) * TLD + kt * 32 + fk];
#pragma unroll
                for (int nt = 0; nt < 4; ++nt) {
                    short8 b = *(const short8*)&Vt[(nt * 16 + fr) * TLD + kt * 32 + fk];
                    o[nt] = __builtin_amdgcn_mfma_f32_16x16x32_bf16(
                        a, b, o[nt], 0, 0, 0);
                }
            }
            float linv[4];
#pragma unroll
            for (int rg = 0; rg < 4; ++rg) linv[rg] = 1.f / rsum[rg];
#pragma unroll
            for (int nt = 0; nt < 4; ++nt)
#pragma unroll
                for (int rg = 0; rg < 4; ++rg) {
                    int row = m0g + q * 4 + rg;
                    st2_wt(AOcur + (size_t)row * 1024 + h * 64 + nt * 16 + fr,
                           f2bf(o[nt][rg] * linv[rg]));
                }
        }
        grid_bar(bar, g, s);   // AO_i complete
    }
}

// ---------------------------------------------------------------------------
extern "C" void kernel_launch(void* const* d_in, const int* in_sizes, int n_in,
                              void* d_out, int out_size, void* d_ws, size_t ws_size,
                              hipStream_t stream)
{
    const float* path   = (const float*)d_in[0];
    const float* w_in1  = (const float*)d_in[1];
    const float* b_in1  = (const float*)d_in[2];
    const float* w_out1 = (const float*)d_in[3];
    const float* b_out1 = (const float*)d_in[4];
    const float* w_lin  = (const float*)d_in[5];
    const float* b_lin  = (const float*)d_in[6];
    const float* w_in2  = (const float*)d_in[7];
    const float* b_in2  = (const float*)d_in[8];
    const float* w_out2 = (const float*)d_in[9];
    const float* b_out2 = (const float*)d_in[10];
    float* out = (float*)d_out;

    // workspace: barriers/bias (16 KB) then bf16 buffers (~58 MB)
    unsigned* bar = (unsigned*)d_ws;                      // 8 KB
    float* bc      = (float*)d_ws + 2048;                 // 2048 fp32
    float* zerosf  = bc + 2048;                           // 1024 fp32
    ushort_t* ws = (ushort_t*)d_ws + 16384;
    ushort_t* path_bf  = ws;                              // 4096*1024
    ushort_t* w_in1_bf = path_bf  + (size_t)4096 * 1024;  // 3072*1024
    ushort_t* w_out1_bf= w_in1_bf + (size_t)3072 * 1024;
    ushort_t* w_lin_bf = w_out1_bf+ (size_t)1024 * 1024;
    ushort_t* w_in2_bf = w_lin_bf + (size_t)1024 * 1024;  // 3072*1024
    ushort_t* w_out2_bf= w_in2_bf + (size_t)3072 * 1024;
    ushort_t* WoT_bf   = w_out2_bf+ (size_t)1024 * 1024;  // 1024*1024
    ushort_t* Wc_bf    = WoT_bf   + (size_t)1024 * 1024;  // 2048*1024
    ushort_t* qkv_bf   = Wc_bf    + (size_t)2048 * 1024;  // 2048*3072
    ushort_t* ybuf_bf  = qkv_bf;                          // alias (qkv dead)
    ushort_t* ao_bf    = qkv_bf   + (size_t)2048 * 3072;  // 2048*1024
    ushort_t* Xchunk   = ao_bf    + (size_t)2048 * 1024;  // 2048*1024
    ushort_t* Qchunk   = Xchunk   + (size_t)2048 * 1024;  // 2048*1024
    ushort_t* AOb      = Qchunk   + (size_t)2048 * 1024;  // 2 x 256*1024
    ushort_t* x0buf    = AOb + 2 * WIN;                   // 256*1024
    ushort_t* dummy    = x0buf + WIN;                     // 256*1024

    hipMemsetAsync(bar, 0, 8192, stream);
    hipMemsetAsync(zerosf, 0, 1024 * sizeof(float), stream);

    cast_bf_k<<<4096, 256, 0, stream>>>(path,  path_bf,  4096 * 1024);
    cast_bf_k<<<3072, 256, 0, stream>>>(w_in1, w_in1_bf, 3072 * 1024);
    cast_bf_k<<<1024, 256, 0, stream>>>(w_out1, w_out1_bf, 1024 * 1024);
    cast_bf_k<<<1024, 256, 0, stream>>>(w_lin, w_lin_bf, 1024 * 1024);
    cast_bf_k<<<3072, 256, 0, stream>>>(w_in2, w_in2_bf, 3072 * 1024);
    cast_bf_k<<<1024, 256, 0, stream>>>(w_out2, w_out2_bf, 1024 * 1024);

    // fused scan weights: Wc = Wkv @ Wo  (bf16), bc = bkv + Wkv @ bo (fp32)
    transpose_k<<<dim3(16, 16), 256, 0, stream>>>(w_out2_bf, WoT_bf);
    bc_k<<<8, 256, 0, stream>>>(w_in2, b_in2, b_out2, bc);
    gemm_bf_k<<<dim3(8, 16), 256, 0, stream>>>(
        w_in2_bf + (size_t)1024 * 1024, 1024, WoT_bf, zerosf,
        Wc_bf, nullptr, 1024, 1024, 0);

    unsigned sbase = 1;
    for (int c = 0; c < NCHUNK; ++c) {
        int w0 = c * CHUNK;
        // ---- Phase 1 for windows [w0, w0+CHUNK) ----
        gemm_qkv_k<<<dim3(24, 16), 256, 0, stream>>>(
            path_bf, w_in1_bf, b_in1, qkv_bf, w0);
        attn_mfma_k<<<dim3(4, NH, CHUNK), 256, 0, stream>>>(qkv_bf, ao_bf);
        gemm_bf_k<<<dim3(8, 16), 256, 0, stream>>>(
            ao_bf, 1024, w_out1_bf, b_out1, ybuf_bf, nullptr, 1024, 1024, 0);
        gemm_bf_k<<<dim3(8, 16), 256, 0, stream>>>(
            ybuf_bf, 1024, w_lin_bf, b_lin, Xchunk, nullptr, 1024, 1024, 1);
        // Q for the whole chunk (rows 0..1023 of w_in2 are wq)
        gemm_bf_k<<<dim3(8, 16), 256, 0, stream>>>(
            Xchunk, 1024, w_in2_bf, b_in2, Qchunk, nullptr, 1024, 1024, 0);

        // ---- Phase 2: one cooperative launch per chunk ----
        if (c == 0) {
            hipMemcpyAsync(x0buf, Xchunk, WIN * sizeof(ushort_t),
                           hipMemcpyDeviceToDevice, stream);
        }
        int i0 = (c == 0) ? 1 : w0;
        int nsteps = (c == 0) ? CHUNK - 1 : CHUNK;
        const ushort_t* QchunkP = Qchunk;
        const ushort_t* x0P = x0buf;
        ushort_t* AObP = AOb;
        const ushort_t* WkvP = w_in2_bf + (size_t)1024 * 1024;
        const float* bkvP = b_in2 + 1024;
        const ushort_t* WcP = Wc_bf;
        const float* bcP = bc;
        unsigned* barP = bar;
        unsigned sb = sbase;
        void* args[] = {&QchunkP, &i0, &w0, &nsteps, &x0P, &AObP,
                        &WkvP, &bkvP, &WcP, &bcP, &barP, &sb};
        hipLaunchCooperativeKernel((void*)scan_coop_k, dim3(64), dim3(256),
                                   args, 0, stream);
        sbase += (unsigned)nsteps;
    }

    // final out-projection: out = AO_239 @ Wo^T + bo  (fp32 to d_out)
    gemm_bf_k<<<dim3(8, 2), 256, 0, stream>>>(
        AOb + (size_t)((N_WIN - 1) & 1) * WIN, 1024, w_out2_bf, b_out2,
        dummy, out, 1024, 1024, 0);
}

// Round 12
// 17071.805 us; speedup vs baseline: 1.5322x; 1.2838x over previous
//
#include <hip/hip_runtime.h>
#include <math.h>

// Problem constants
#define D_MODEL 1024
#define N_WIN   240
#define TOK     256
#define NH      16
#define DH      64
#define CHUNK   8
#define NCHUNK  30
#define WIN     ((size_t)TOK * D_MODEL)

typedef unsigned short ushort_t;
typedef unsigned long long ull_t;
typedef __attribute__((ext_vector_type(8))) short short8;
typedef __attribute__((ext_vector_type(4))) float floatx4;

__device__ __forceinline__ ushort_t f2bf(float f) {   // RNE
    unsigned u = __float_as_uint(f);
    unsigned lsb = (u >> 16) & 1u;
    u += 0x7fffu + lsb;
    return (ushort_t)(u >> 16);
}

// ---------------------------------------------------------------------------
// Coherence scheme (round-12):
//  - Cross-step AO data rotates through 8 unique slots (slot = step & 7).
//    Within one 8-step launch no slot is read before it is written, so
//    normal CACHED loads are safe: reader L2s were invalidated at launch
//    start (HIP inter-kernel acquire) and first touch fetches fresh data
//    from the IC, where the producer's write-through stores landed.
//  - st2_wt: 2B write-through store (sc1) -> coherence point (IC).
//  - Barriers: agent-scope atomics, no cache maintenance.
// ---------------------------------------------------------------------------
__device__ __forceinline__ void st2_wt(ushort_t* p, ushort_t v) {
    unsigned vv = v;
    asm volatile("global_store_short %0, %1, off sc1"
                 :: "v"(p), "v"(vv) : "memory");
}
__device__ __forceinline__ void rel_drain() {
    asm volatile("s_waitcnt vmcnt(0)" ::: "memory");
}

// async global->LDS, 16B per lane (phase-1 GEMM staging)
#define GLDS(g, l) __builtin_amdgcn_global_load_lds( \
    (const __attribute__((address_space(1))) unsigned int*)(g), \
    (__attribute__((address_space(3))) unsigned int*)(l), 16, 0, 0)

// ---------------------------------------------------------------------------
// Grid barrier (tree, fence-free): all threads drain stores, WG syncs, tid0
// signals agent-scope counters and spins on release. 8 subs x 8 arrivals.
// ---------------------------------------------------------------------------
__device__ __forceinline__ void grid_bar(unsigned* base, int g, unsigned s)
{
    rel_drain();
    __syncthreads();
    if (threadIdx.x == 0) {
        unsigned old = __hip_atomic_fetch_add(base + g * 32, 1u,
                __ATOMIC_RELAXED, __HIP_MEMORY_SCOPE_AGENT);
        if (old == 8u * s - 1u) {
            unsigned r = __hip_atomic_fetch_add(base + 256, 1u,
                    __ATOMIC_RELAXED, __HIP_MEMORY_SCOPE_AGENT);
            if (r == 8u * s - 1u)
                __hip_atomic_store(base + 288, s, __ATOMIC_RELAXED,
                                   __HIP_MEMORY_SCOPE_AGENT);
        }
        while (__hip_atomic_load(base + 288, __ATOMIC_RELAXED,
                                 __HIP_MEMORY_SCOPE_AGENT) < s)
            __builtin_amdgcn_s_sleep(1);
    }
    __syncthreads();
}

// ---------------------------------------------------------------------------
// fp32 -> bf16 cast
// ---------------------------------------------------------------------------
__global__ __launch_bounds__(256) void cast_bf_k(
    const float* __restrict__ s, ushort_t* __restrict__ d, int n)
{
    int i = (blockIdx.x * 256 + threadIdx.x) * 4;
    if (i >= n) return;
    float4 v = *(const float4*)(s + i);
    ushort4 o;
    o.x = f2bf(v.x); o.y = f2bf(v.y); o.z = f2bf(v.z); o.w = f2bf(v.w);
    *(ushort4*)(d + i) = o;
}

// 64x64-tile bf16 transpose: dst[c][r] = src[r][c], both 1024x1024
__global__ __launch_bounds__(256) void transpose_k(
    const ushort_t* __restrict__ src, ushort_t* __restrict__ dst)
{
    __shared__ ushort_t t[64][65];
    const int bx = blockIdx.x * 64, by = blockIdx.y * 64;
    const int c = threadIdx.x & 63, r0 = threadIdx.x >> 6;
#pragma unroll
    for (int k = 0; k < 16; ++k) {
        int r = r0 + k * 4;
        t[r][c] = src[(size_t)(by + r) * 1024 + bx + c];
    }
    __syncthreads();
#pragma unroll
    for (int k = 0; k < 16; ++k) {
        int r = r0 + k * 4;
        dst[(size_t)(bx + r) * 1024 + by + c] = t[c][r];
    }
}

// bc[n] = b_in2[1024+n] + dot(w_in2 row (1024+n), b_out2), fp32, n in [0,2048)
__global__ __launch_bounds__(256) void bc_k(
    const float* __restrict__ w_in2, const float* __restrict__ b_in2,
    const float* __restrict__ b_out2, float* __restrict__ bc)
{
    int n = blockIdx.x * 256 + threadIdx.x;
    const float* row = w_in2 + (size_t)(1024 + n) * 1024;
    float s = b_in2[1024 + n];
    for (int j = 0; j < 1024; j += 4) {
        float4 w = *(const float4*)(row + j);
        float4 b = *(const float4*)(b_out2 + j);
        s += w.x * b.x + w.y * b.y + w.z * b.z + w.w * b.w;
    }
    bc[n] = s;
}

// ---------------------------------------------------------------------------
// Phase-1 bf16 MFMA GEMM core (m97 structure), 128x128 tile, BK=32.
// ---------------------------------------------------------------------------
template<bool GATHER>
__device__ __forceinline__ void gemm_core(
    const ushort_t* __restrict__ A, int lda, int w0,
    const ushort_t* __restrict__ W, const float* __restrict__ bias,
    ushort_t* __restrict__ Cb, float* __restrict__ Cf, int ldc,
    int K, int m0, int n0, int co, int relu)
{
    __shared__ ushort_t As[128 * 32];
    __shared__ ushort_t Bs[128 * 32];
    const int tid = threadIdx.x;
    const int wave = tid >> 6, lane = tid & 63;
    const int wm = wave & 1, wn = wave >> 1;

    int r0 = m0 + (tid >> 2), r1 = r0 + 64;
    if (GATHER) {
        r0 = (w0 + (r0 >> 8)) * 16 + (r0 & 255);
        r1 = (w0 + (r1 >> 8)) * 16 + (r1 & 255);
    }
    const int kcol = (tid & 3) * 8;
    const ushort_t* gA0 = A + (size_t)r0 * lda + kcol;
    const ushort_t* gA1 = A + (size_t)r1 * lda + kcol;
    const ushort_t* pW  = W + (size_t)n0 * K;
    const ushort_t* gB0 = pW + (size_t)(tid >> 2) * K + kcol;
    const ushort_t* gB1 = gB0 + (size_t)64 * K;
    ushort_t* lA = As + wave * 512;
    ushort_t* lB = Bs + wave * 512;

    floatx4 acc[4][4];
#pragma unroll
    for (int i = 0; i < 4; ++i)
#pragma unroll
        for (int j = 0; j < 4; ++j) acc[i][j] = (floatx4){0.f, 0.f, 0.f, 0.f};

    const int fr = lane & 15, fk = (lane >> 4) * 8;
    const int arow = (wm * 64 + fr) * 32 + fk;
    const int brow = (wn * 64 + fr) * 32 + fk;

    for (int k0 = 0; k0 < K; k0 += 32) {
        GLDS(gA0 + k0, lA);
        GLDS(gA1 + k0, lA + 2048);
        GLDS(gB0 + k0, lB);
        GLDS(gB1 + k0, lB + 2048);
        __syncthreads();
        short8 a[4], b[4];
#pragma unroll
        for (int mi = 0; mi < 4; ++mi) a[mi] = *(const short8*)&As[arow + mi * 512];
#pragma unroll
        for (int ni = 0; ni < 4; ++ni) b[ni] = *(const short8*)&Bs[brow + ni * 512];
#pragma unroll
        for (int mi = 0; mi < 4; ++mi)
#pragma unroll
            for (int ni = 0; ni < 4; ++ni)
                acc[mi][ni] = __builtin_amdgcn_mfma_f32_16x16x32_bf16(
                    a[mi], b[ni], acc[mi][ni], 0, 0, 0);
        __syncthreads();
    }

    const int crq = (lane >> 4) * 4;
    const int ccol = lane & 15;
#pragma unroll
    for (int mi = 0; mi < 4; ++mi) {
#pragma unroll
        for (int ni = 0; ni < 4; ++ni) {
            int lc = wn * 64 + ni * 16 + ccol;
            float bz = bias[n0 + lc];
#pragma unroll
            for (int rg = 0; rg < 4; ++rg) {
                int row = m0 + wm * 64 + mi * 16 + crq + rg;
                float v = acc[mi][ni][rg] + bz;
                if (relu) v = fmaxf(v, 0.f);
                size_t off = (size_t)row * ldc + co + lc;
                if (Cb) Cb[off] = f2bf(v);
                if (Cf) Cf[off] = v;
            }
        }
    }
}

__global__ __launch_bounds__(256) void gemm_bf_k(
    const ushort_t* __restrict__ A, int lda,
    const ushort_t* __restrict__ W, const float* __restrict__ bias,
    ushort_t* __restrict__ Cb, float* __restrict__ Cf, int ldc,
    int K, int relu)
{
    gemm_core<false>(A, lda, 0, W, bias, Cb, Cf, ldc, K,
                     blockIdx.y * 128, blockIdx.x * 128, blockIdx.x * 128, relu);
}

__global__ __launch_bounds__(256) void gemm_qkv_k(
    const ushort_t* __restrict__ path_bf, const ushort_t* __restrict__ W,
    const float* __restrict__ bias, ushort_t* __restrict__ Cb, int w0)
{
    gemm_core<true>(path_bf, 1024, w0, W, bias, Cb, nullptr, 3072, 1024,
                    blockIdx.y * 128, blockIdx.x * 128, blockIdx.x * 128, 0);
}

// ---------------------------------------------------------------------------
// Phase-1 MFMA attention (unchanged).
// ---------------------------------------------------------------------------
#define PLD 260
#define VLD 132

struct AttnShared {
    ushort_t P[64 * PLD];
    ushort_t VT[64 * VLD];
    float    l[64];
};

__global__ __launch_bounds__(256) void attn_mfma_k(
    const ushort_t* __restrict__ qkv, ushort_t* __restrict__ ao)
{
    __shared__ AttnShared sh;
    const int rs = blockIdx.x, h = blockIdx.y, b = blockIdx.z;
    const ushort_t* base = qkv + (size_t)b * TOK * 3072;
    const ushort_t* Q = base;
    const ushort_t* K = base + 1024;
    const ushort_t* V = base + 2048;
    ushort_t* O = ao + (size_t)b * TOK * 1024;
    const int ldq = 3072, ldkv = 3072, ldo = 1024;
    const int tid = threadIdx.x;
    const int wave = tid >> 6, lane = tid & 63;
    const int fr = lane & 15, q = lane >> 4, fk = q * 8;
    const ushort_t* Qh = Q + (size_t)(rs * 64) * ldq + h * 64;
    const ushort_t* Kh = K + h * 64;
    const ushort_t* Vh = V + h * 64;
    const int m0 = wave * 16;

    floatx4 s[16];
#pragma unroll
    for (int nt = 0; nt < 16; ++nt) s[nt] = (floatx4){0.f, 0.f, 0.f, 0.f};
#pragma unroll
    for (int kc = 0; kc < 64; kc += 32) {
        short8 a = *(const short8*)(Qh + (size_t)(m0 + fr) * ldq + kc + fk);
#pragma unroll
        for (int nt = 0; nt < 16; ++nt) {
            short8 b = *(const short8*)(Kh + (size_t)(nt * 16 + fr) * ldkv + kc + fk);
            s[nt] = __builtin_amdgcn_mfma_f32_16x16x32_bf16(a, b, s[nt], 0, 0, 0);
        }
    }

    float rmax[4] = {-INFINITY, -INFINITY, -INFINITY, -INFINITY};
#pragma unroll
    for (int nt = 0; nt < 16; ++nt)
#pragma unroll
        for (int rg = 0; rg < 4; ++rg) rmax[rg] = fmaxf(rmax[rg], s[nt][rg]);
#pragma unroll
    for (int d = 1; d < 16; d <<= 1)
#pragma unroll
        for (int rg = 0; rg < 4; ++rg)
            rmax[rg] = fmaxf(rmax[rg], __shfl_xor(rmax[rg], d));

    float rsum[4] = {0.f, 0.f, 0.f, 0.f};
#pragma unroll
    for (int nt = 0; nt < 16; ++nt) {
#pragma unroll
        for (int rg = 0; rg < 4; ++rg) {
            float p = __expf((s[nt][rg] - rmax[rg]) * 0.125f);
            rsum[rg] += p;
            sh.P[(m0 + q * 4 + rg) * PLD + nt * 16 + fr] = f2bf(p);
        }
    }
#pragma unroll
    for (int d = 1; d < 16; d <<= 1)
#pragma unroll
        for (int rg = 0; rg < 4; ++rg) rsum[rg] += __shfl_xor(rsum[rg], d);
    if (fr == 0) {
#pragma unroll
        for (int rg = 0; rg < 4; ++rg) sh.l[m0 + q * 4 + rg] = rsum[rg];
    }
    __syncthreads();

    floatx4 o[4];
#pragma unroll
    for (int i = 0; i < 4; ++i) o[i] = (floatx4){0.f, 0.f, 0.f, 0.f};

#pragma unroll
    for (int half = 0; half < 2; ++half) {
        {
            int r = tid & 127, cp = tid >> 7;
            const ushort_t* vrow = Vh + (size_t)(half * 128 + r) * ldkv + cp * 32;
#pragma unroll
            for (int c = 0; c < 4; ++c) {
                uint4 pk = *(const uint4*)(vrow + c * 8);
                int d0 = cp * 32 + c * 8;
                sh.VT[(d0 + 0) * VLD + r] = (ushort_t)(pk.x & 0xffff);
                sh.VT[(d0 + 1) * VLD + r] = (ushort_t)(pk.x >> 16);
                sh.VT[(d0 + 2) * VLD + r] = (ushort_t)(pk.y & 0xffff);
                sh.VT[(d0 + 3) * VLD + r] = (ushort_t)(pk.y >> 16);
                sh.VT[(d0 + 4) * VLD + r] = (ushort_t)(pk.z & 0xffff);
                sh.VT[(d0 + 5) * VLD + r] = (ushort_t)(pk.z >> 16);
                sh.VT[(d0 + 6) * VLD + r] = (ushort_t)(pk.w & 0xffff);
                sh.VT[(d0 + 7) * VLD + r] = (ushort_t)(pk.w >> 16);
            }
        }
        __syncthreads();
#pragma unroll
        for (int ks = 0; ks < 4; ++ks) {
            short8 a = *(const short8*)&sh.P[(m0 + fr) * PLD + half * 128 + ks * 32 + fk];
#pragma unroll
            for (int nt2 = 0; nt2 < 4; ++nt2) {
                short8 b = *(const short8*)&sh.VT[(nt2 * 16 + fr) * VLD + ks * 32 + fk];
                o[nt2] = __builtin_amdgcn_mfma_f32_16x16x32_bf16(a, b, o[nt2], 0, 0, 0);
            }
        }
        __syncthreads();
    }

    float linv[4];
#pragma unroll
    for (int rg = 0; rg < 4; ++rg) linv[rg] = 1.f / sh.l[m0 + q * 4 + rg];
#pragma unroll
    for (int nt2 = 0; nt2 < 4; ++nt2)
#pragma unroll
        for (int rg = 0; rg < 4; ++rg) {
            int row = rs * 64 + m0 + q * 4 + rg;
            O[(size_t)row * ldo + h * 64 + nt2 * 16 + fr] =
                f2bf(o[nt2][rg] * linv[rg]);
        }
}

// ===========================================================================
// Cooperative phase-2 kernel: round-11 layout, AO slot rotation + CACHED
// A reads. Grid 64 WGs x 256 thr. WG = (head h = wg>>2, row-slice rs = wg&3).
// Per step i:
//   KV_i = A @ Wsel^T + bsel, A = AOslots[(i-1)&7] via cached short8 loads
//   (i==1: A = x0, Wsel = Wkv). Wave w builds keys [w*64, +64) -> LDS.
//   __syncthreads -> attn rows [rs*64, +64) -> AOslots[i&7] via st2_wt ->
//   ONE grid barrier. Final out-proj is a plain GEMM after all chunks.
// ===========================================================================
#define KLD 72    // K stride (144 B)
#define TLD 264   // Vt / P stride (528 B)

__global__ __launch_bounds__(256, 1) void scan_coop_k(
    const ushort_t* __restrict__ Qchunk, int i0, int w0, int nsteps,
    const ushort_t* __restrict__ x0, ushort_t* __restrict__ AOb,
    const ushort_t* __restrict__ Wkv, const float* __restrict__ bkv,
    const ushort_t* __restrict__ Wc, const float* __restrict__ bc,
    unsigned* __restrict__ bar, unsigned s0)
{
    __shared__ ushort_t Kl[256 * KLD];
    __shared__ ushort_t Vt[64 * TLD];
    __shared__ ushort_t P[64 * TLD];
    const int wg = blockIdx.x, tid = threadIdx.x;
    const int h = wg >> 2, rs = wg & 3;
    const int wave = tid >> 6, lane = tid & 63;
    const int fr = lane & 15, q = lane >> 4, fk = q * 8;
    const int g = wg & 7;

    unsigned s = s0;
    for (int t = 0; t < nsteps; ++t, ++s) {
        const int i = i0 + t;
        const ushort_t* Asrc;
        const ushort_t* Wsel;
        const float* bsel;
        if (i == 1) { Asrc = x0; Wsel = Wkv; bsel = bkv; }
        else {
            Asrc = AOb + (size_t)((i - 1) & 7) * WIN;   // unique slot/step
            Wsel = Wc; bsel = bc;
        }

        // ---------- KV build: wave w -> keys [w*64, w*64+64) ----------
        {
            floatx4 acc[4][8];
#pragma unroll
            for (int mt = 0; mt < 4; ++mt)
#pragma unroll
                for (int nt = 0; nt < 8; ++nt)
                    acc[mt][nt] = (floatx4){0.f, 0.f, 0.f, 0.f};
            const ushort_t* arow = Asrc + (size_t)(wave * 64 + fr) * 1024 + fk;
            const ushort_t* wrow[8];
#pragma unroll
            for (int nt = 0; nt < 8; ++nt) {
                int n = ((nt >> 2) << 10) + h * 64 + (nt & 3) * 16 + fr;
                wrow[nt] = Wsel + (size_t)n * 1024 + fk;
            }
            // 2-iteration register prefetch of the (cached) A loads
            short8 a0[4], a1[4];
#pragma unroll
            for (int mt = 0; mt < 4; ++mt)
                a0[mt] = *(const short8*)(arow + (size_t)(mt * 16) * 1024);
#pragma unroll
            for (int mt = 0; mt < 4; ++mt)
                a1[mt] = *(const short8*)(arow + (size_t)(mt * 16) * 1024 + 32);
            for (int k0 = 0; k0 < 1024; k0 += 64) {
                short8 a2[4], a3[4];
#pragma unroll
                for (int mt = 0; mt < 4; ++mt)   // overread past end is benign
                    a2[mt] = *(const short8*)(arow + (size_t)(mt * 16) * 1024 + k0 + 64);
#pragma unroll
                for (int mt = 0; mt < 4; ++mt)
                    a3[mt] = *(const short8*)(arow + (size_t)(mt * 16) * 1024 + k0 + 96);
#pragma unroll
                for (int nt = 0; nt < 8; ++nt) {
                    short8 b = *(const short8*)(wrow[nt] + k0);
#pragma unroll
                    for (int mt = 0; mt < 4; ++mt)
                        acc[mt][nt] = __builtin_amdgcn_mfma_f32_16x16x32_bf16(
                            a0[mt], b, acc[mt][nt], 0, 0, 0);
                }
#pragma unroll
                for (int nt = 0; nt < 8; ++nt) {
                    short8 b = *(const short8*)(wrow[nt] + k0 + 32);
#pragma unroll
                    for (int mt = 0; mt < 4; ++mt)
                        acc[mt][nt] = __builtin_amdgcn_mfma_f32_16x16x32_bf16(
                            a1[mt], b, acc[mt][nt], 0, 0, 0);
                }
#pragma unroll
                for (int mt = 0; mt < 4; ++mt) { a0[mt] = a2[mt]; a1[mt] = a3[mt]; }
            }
            // epilogue: K -> Kl[key][dim], V -> Vt[dim][key]
#pragma unroll
            for (int mt = 0; mt < 4; ++mt) {
                const int kb = wave * 64 + mt * 16;
#pragma unroll
                for (int nt = 0; nt < 4; ++nt) {
                    float bzk = bsel[h * 64 + nt * 16 + fr];
#pragma unroll
                    for (int rg = 0; rg < 4; ++rg)
                        Kl[(kb + q * 4 + rg) * KLD + nt * 16 + fr] =
                            f2bf(acc[mt][nt][rg] + bzk);
                    float bzv = bsel[1024 + h * 64 + nt * 16 + fr];
                    ushort4 pv;
                    pv.x = f2bf(acc[mt][nt + 4][0] + bzv);
                    pv.y = f2bf(acc[mt][nt + 4][1] + bzv);
                    pv.z = f2bf(acc[mt][nt + 4][2] + bzv);
                    pv.w = f2bf(acc[mt][nt + 4][3] + bzv);
                    *(ushort4*)&Vt[(nt * 16 + fr) * TLD + kb + q * 4] = pv;
                }
            }
        }
        __syncthreads();

        // ---------- attention: wave w -> rows rs*64 + w*16 .. +16 ----------
        ushort_t* AOcur = AOb + (size_t)(i & 7) * WIN;
        {
            const int m0g = rs * 64 + wave * 16;    // global Q row base
            const int pl0 = wave * 16;              // local P row base
            const ushort_t* Qrow = Qchunk + (size_t)(i - w0) * WIN
                + (size_t)(m0g + fr) * 1024 + h * 64;
            floatx4 sc[16];
#pragma unroll
            for (int nt = 0; nt < 16; ++nt) sc[nt] = (floatx4){0.f, 0.f, 0.f, 0.f};
#pragma unroll
            for (int kc = 0; kc < 64; kc += 32) {
                short8 a = *(const short8*)(Qrow + kc);
#pragma unroll
                for (int nt = 0; nt < 16; ++nt) {
                    short8 b = *(const short8*)&Kl[(nt * 16 + fr) * KLD + kc + fk];
                    sc[nt] = __builtin_amdgcn_mfma_f32_16x16x32_bf16(
                        a, b, sc[nt], 0, 0, 0);
                }
            }
            float rmax[4] = {-INFINITY, -INFINITY, -INFINITY, -INFINITY};
#pragma unroll
            for (int nt = 0; nt < 16; ++nt)
#pragma unroll
                for (int rg = 0; rg < 4; ++rg) rmax[rg] = fmaxf(rmax[rg], sc[nt][rg]);
#pragma unroll
            for (int d = 1; d < 16; d <<= 1)
#pragma unroll
                for (int rg = 0; rg < 4; ++rg)
                    rmax[rg] = fmaxf(rmax[rg], __shfl_xor(rmax[rg], d));
            float rsum[4] = {0.f, 0.f, 0.f, 0.f};
#pragma unroll
            for (int nt = 0; nt < 16; ++nt) {
#pragma unroll
                for (int rg = 0; rg < 4; ++rg) {
                    float p = __expf((sc[nt][rg] - rmax[rg]) * 0.125f);
                    rsum[rg] += p;
                    P[(pl0 + q * 4 + rg) * TLD + nt * 16 + fr] = f2bf(p);
                }
            }
#pragma unroll
            for (int d = 1; d < 16; d <<= 1)
#pragma unroll
                for (int rg = 0; rg < 4; ++rg) rsum[rg] += __shfl_xor(rsum[rg], d);

            floatx4 o[4];
#pragma unroll
            for (int nt = 0; nt < 4; ++nt) o[nt] = (floatx4){0.f, 0.f, 0.f, 0.f};
#pragma unroll
            for (int kt = 0; kt < 8; ++kt) {
                short8 a = *(const short8*)&P[(pl0 + fr) * TLD + kt * 32 + fk];
#pragma unroll
                for (int nt = 0; nt < 4; ++nt) {
                    short8 b = *(const short8*)&Vt[(nt * 16 + fr) * TLD + kt * 32 + fk];
                    o[nt] = __builtin_amdgcn_mfma_f32_16x16x32_bf16(
                        a, b, o[nt], 0, 0, 0);
                }
            }
            float linv[4];
#pragma unroll
            for (int rg = 0; rg < 4; ++rg) linv[rg] = 1.f / rsum[rg];
#pragma unroll
            for (int nt = 0; nt < 4; ++nt)
#pragma unroll
                for (int rg = 0; rg < 4; ++rg) {
                    int row = m0g + q * 4 + rg;
                    st2_wt(AOcur + (size_t)row * 1024 + h * 64 + nt * 16 + fr,
                           f2bf(o[nt][rg] * linv[rg]));
                }
        }
        grid_bar(bar, g, s);   // AO_i complete
    }
}

// ---------------------------------------------------------------------------
extern "C" void kernel_launch(void* const* d_in, const int* in_sizes, int n_in,
                              void* d_out, int out_size, void* d_ws, size_t ws_size,
                              hipStream_t stream)
{
    const float* path   = (const float*)d_in[0];
    const float* w_in1  = (const float*)d_in[1];
    const float* b_in1  = (const float*)d_in[2];
    const float* w_out1 = (const float*)d_in[3];
    const float* b_out1 = (const float*)d_in[4];
    const float* w_lin  = (const float*)d_in[5];
    const float* b_lin  = (const float*)d_in[6];
    const float* w_in2  = (const float*)d_in[7];
    const float* b_in2  = (const float*)d_in[8];
    const float* w_out2 = (const float*)d_in[9];
    const float* b_out2 = (const float*)d_in[10];
    float* out = (float*)d_out;

    // workspace: barriers/bias (16 KB) then bf16 buffers (~62 MB)
    unsigned* bar = (unsigned*)d_ws;                      // 8 KB
    float* bc      = (float*)d_ws + 2048;                 // 2048 fp32
    float* zerosf  = bc + 2048;                           // 1024 fp32
    ushort_t* ws = (ushort_t*)d_ws + 16384;
    ushort_t* path_bf  = ws;                              // 4096*1024
    ushort_t* w_in1_bf = path_bf  + (size_t)4096 * 1024;  // 3072*1024
    ushort_t* w_out1_bf= w_in1_bf + (size_t)3072 * 1024;
    ushort_t* w_lin_bf = w_out1_bf+ (size_t)1024 * 1024;
    ushort_t* w_in2_bf = w_lin_bf + (size_t)1024 * 1024;  // 3072*1024
    ushort_t* w_out2_bf= w_in2_bf + (size_t)3072 * 1024;
    ushort_t* WoT_bf   = w_out2_bf+ (size_t)1024 * 1024;  // 1024*1024
    ushort_t* Wc_bf    = WoT_bf   + (size_t)1024 * 1024;  // 2048*1024
    ushort_t* qkv_bf   = Wc_bf    + (size_t)2048 * 1024;  // 2048*3072
    ushort_t* ybuf_bf  = qkv_bf;                          // alias (qkv dead)
    ushort_t* ao_bf    = qkv_bf   + (size_t)2048 * 3072;  // 2048*1024
    ushort_t* Xchunk   = ao_bf    + (size_t)2048 * 1024;  // 2048*1024
    ushort_t* Qchunk   = Xchunk   + (size_t)2048 * 1024;  // 2048*1024
    ushort_t* AOb      = Qchunk   + (size_t)2048 * 1024;  // 8 x 256*1024
    ushort_t* x0buf    = AOb + 8 * WIN;                   // 256*1024
    ushort_t* dummy    = x0buf + WIN;                     // 256*1024

    hipMemsetAsync(bar, 0, 8192, stream);
    hipMemsetAsync(zerosf, 0, 1024 * sizeof(float), stream);

    cast_bf_k<<<4096, 256, 0, stream>>>(path,  path_bf,  4096 * 1024);
    cast_bf_k<<<3072, 256, 0, stream>>>(w_in1, w_in1_bf, 3072 * 1024);
    cast_bf_k<<<1024, 256, 0, stream>>>(w_out1, w_out1_bf, 1024 * 1024);
    cast_bf_k<<<1024, 256, 0, stream>>>(w_lin, w_lin_bf, 1024 * 1024);
    cast_bf_k<<<3072, 256, 0, stream>>>(w_in2, w_in2_bf, 3072 * 1024);
    cast_bf_k<<<1024, 256, 0, stream>>>(w_out2, w_out2_bf, 1024 * 1024);

    // fused scan weights: Wc = Wkv @ Wo  (bf16), bc = bkv + Wkv @ bo (fp32)
    transpose_k<<<dim3(16, 16), 256, 0, stream>>>(w_out2_bf, WoT_bf);
    bc_k<<<8, 256, 0, stream>>>(w_in2, b_in2, b_out2, bc);
    gemm_bf_k<<<dim3(8, 16), 256, 0, stream>>>(
        w_in2_bf + (size_t)1024 * 1024, 1024, WoT_bf, zerosf,
        Wc_bf, nullptr, 1024, 1024, 0);

    unsigned sbase = 1;
    for (int c = 0; c < NCHUNK; ++c) {
        int w0 = c * CHUNK;
        // ---- Phase 1 for windows [w0, w0+CHUNK) ----
        gemm_qkv_k<<<dim3(24, 16), 256, 0, stream>>>(
            path_bf, w_in1_bf, b_in1, qkv_bf, w0);
        attn_mfma_k<<<dim3(4, NH, CHUNK), 256, 0, stream>>>(qkv_bf, ao_bf);
        gemm_bf_k<<<dim3(8, 16), 256, 0, stream>>>(
            ao_bf, 1024, w_out1_bf, b_out1, ybuf_bf, nullptr, 1024, 1024, 0);
        gemm_bf_k<<<dim3(8, 16), 256, 0, stream>>>(
            ybuf_bf, 1024, w_lin_bf, b_lin, Xchunk, nullptr, 1024, 1024, 1);
        // Q for the whole chunk (rows 0..1023 of w_in2 are wq)
        gemm_bf_k<<<dim3(8, 16), 256, 0, stream>>>(
            Xchunk, 1024, w_in2_bf, b_in2, Qchunk, nullptr, 1024, 1024, 0);

        // ---- Phase 2: one cooperative launch per chunk ----
        if (c == 0) {
            hipMemcpyAsync(x0buf, Xchunk, WIN * sizeof(ushort_t),
                           hipMemcpyDeviceToDevice, stream);
        }
        int i0 = (c == 0) ? 1 : w0;
        int nsteps = (c == 0) ? CHUNK - 1 : CHUNK;
        const ushort_t* QchunkP = Qchunk;
        const ushort_t* x0P = x0buf;
        ushort_t* AObP = AOb;
        const ushort_t* WkvP = w_in2_bf + (size_t)1024 * 1024;
        const float* bkvP = b_in2 + 1024;
        const ushort_t* WcP = Wc_bf;
        const float* bcP = bc;
        unsigned* barP = bar;
        unsigned sb = sbase;
        void* args[] = {&QchunkP, &i0, &w0, &nsteps, &x0P, &AObP,
                        &WkvP, &bkvP, &WcP, &bcP, &barP, &sb};
        hipLaunchCooperativeKernel((void*)scan_coop_k, dim3(64), dim3(256),
                                   args, 0, stream);
        sbase += (unsigned)nsteps;
    }

    // final out-projection: out = AO_239 @ Wo^T + bo  (fp32 to d_out)
    gemm_bf_k<<<dim3(8, 2), 256, 0, stream>>>(
        AOb + (size_t)((N_WIN - 1) & 7) * WIN, 1024, w_out2_bf, b_out2,
        dummy, out, 1024, 1024, 0);
}